// Round 7
// baseline (132.641 us; speedup 1.0000x reference)
//
#include <hip/hip_runtime.h>
#include <hip/hip_bf16.h>
#include <math.h>

#define SEQ    2048
#define DH     64
#define EMB    512
#define INDIM  512
#define NHEADS 8
#define BATCH  4
#define MTOT   (BATCH * SEQ)   // 8192

typedef __attribute__((ext_vector_type(8))) short bf16x8;   // 8 bf16 = 4 VGPR
typedef __attribute__((ext_vector_type(4))) float f32x4;

__device__ __forceinline__ ushort f2bf(float x) {
  union { float f; unsigned u; } v; v.f = x;
  unsigned r = v.u + 0x7FFFu + ((v.u >> 16) & 1u);   // RNE
  return (ushort)(r >> 16);
}

// packed f32x2 -> bf16x2 (T12 recipe: no builtin on gfx950, single HW op)
__device__ __forceinline__ unsigned cvt_pk_bf16(float lo, float hi) {
  unsigned r;
  asm("v_cvt_pk_bf16_f32 %0, %1, %2" : "=v"(r) : "v"(lo), "v"(hi));
  return r;
}

// raw v_exp_f32 (exp2). Args here are |x| < ~40 -> no range handling needed.
__device__ __forceinline__ float fast_exp2(float x) {
  float r;
  asm("v_exp_f32 %0, %1" : "=v"(r) : "v"(x));
  return r;
}

// ---------------------------------------------------------------------------
// f32 -> bf16 conversion, 8 elems/thread
// ---------------------------------------------------------------------------
__global__ __launch_bounds__(256) void conv_bf16(const float* __restrict__ src,
                                                 ushort* __restrict__ dst, int n8) {
  const int i = blockIdx.x * 256 + threadIdx.x;
  if (i >= n8) return;
  const float4 a = ((const float4*)src)[i * 2];
  const float4 b = ((const float4*)src)[i * 2 + 1];
  uint4 o;
  o.x = cvt_pk_bf16(a.x, a.y);
  o.y = cvt_pk_bf16(a.z, a.w);
  o.z = cvt_pk_bf16(b.x, b.y);
  o.w = cvt_pk_bf16(b.z, b.w);
  ((uint4*)dst)[i] = o;
}

// 4 weight matrices in one launch (blockIdx.y selects)
__global__ __launch_bounds__(256) void conv_bf16_w4(
    const float* __restrict__ w0, const float* __restrict__ w1,
    const float* __restrict__ w2, const float* __restrict__ w3,
    ushort* __restrict__ dst, int n8per) {
  const int i = blockIdx.x * 256 + threadIdx.x;
  if (i >= n8per) return;
  const float* src = (blockIdx.y == 0) ? w0 : (blockIdx.y == 1) ? w1
                   : (blockIdx.y == 2) ? w2 : w3;
  ushort* d = dst + (size_t)blockIdx.y * n8per * 8;
  const float4 a = ((const float4*)src)[i * 2];
  const float4 b = ((const float4*)src)[i * 2 + 1];
  uint4 o;
  o.x = cvt_pk_bf16(a.x, a.y);
  o.y = cvt_pk_bf16(a.z, a.w);
  o.z = cvt_pk_bf16(b.x, b.y);
  o.w = cvt_pk_bf16(b.z, b.w);
  ((uint4*)d)[i] = o;
}

// ---------------------------------------------------------------------------
// MFMA GEMM, m97 structure: 128x128 tile, BK=32, 4 waves, 4x4 16x16 frags/wave,
// global_load_lds width 16.
// MODE 0: fused QKV (N=1536). which=bn>>9: 0->Q (pre-scaled by 0.125*log2e),
//         1->K bf16 [B,H,N,Dh]; 2->V^T bf16 [B,H,Dh,N] via LDS transpose.
// MODE 1: out-projection, f32 out [M][EMB] + bias.
// ---------------------------------------------------------------------------
template <int MODE>
__global__ __launch_bounds__(256) void mfma_gemm(
    const ushort* __restrict__ A, const ushort* __restrict__ W,
    const float* __restrict__ b0, const float* __restrict__ b1,
    const float* __restrict__ b2,
    ushort* __restrict__ outQ, ushort* __restrict__ outK,
    ushort* __restrict__ outVT, float* __restrict__ outF) {
  __shared__ __align__(16) char smem[MODE == 0 ? 35840 : 16384];
  ushort* As = (ushort*)smem;            // [128][32] bf16 = 8 KB
  ushort* Bs = (ushort*)(smem + 8192);   // [128][32] bf16 = 8 KB
  ushort* Tl = (ushort*)smem;            // epilogue transpose [128][140]

  const int bm = blockIdx.x * 128;
  const int bn = blockIdx.y * 128;
  const int tid = threadIdx.x;
  const int wave = tid >> 6, lane = tid & 63;
  const int g = lane >> 4, ln = lane & 15;
  const int wr = wave >> 1, wc = wave & 1;

  f32x4 acc[4][4];
#pragma unroll
  for (int m = 0; m < 4; ++m)
#pragma unroll
    for (int n = 0; n < 4; ++n) acc[m][n] = (f32x4){0.f, 0.f, 0.f, 0.f};

  const size_t a_base = (size_t)(bm + wave * 16 + (lane >> 2)) * INDIM + (lane & 3) * 8;
  const size_t b_base = (size_t)(bn + wave * 16 + (lane >> 2)) * INDIM + (lane & 3) * 8;
  ushort* ldsA0 = As + wave * 512;
  ushort* ldsA1 = As + 2048 + wave * 512;
  ushort* ldsB0 = Bs + wave * 512;
  ushort* ldsB1 = Bs + 2048 + wave * 512;

  for (int k0 = 0; k0 < INDIM; k0 += 32) {
    __syncthreads();
    __builtin_amdgcn_global_load_lds(
        (const __attribute__((address_space(1))) void*)(A + a_base + k0),
        (__attribute__((address_space(3))) void*)ldsA0, 16, 0, 0);
    __builtin_amdgcn_global_load_lds(
        (const __attribute__((address_space(1))) void*)(A + a_base + 64 * INDIM + k0),
        (__attribute__((address_space(3))) void*)ldsA1, 16, 0, 0);
    __builtin_amdgcn_global_load_lds(
        (const __attribute__((address_space(1))) void*)(W + b_base + k0),
        (__attribute__((address_space(3))) void*)ldsB0, 16, 0, 0);
    __builtin_amdgcn_global_load_lds(
        (const __attribute__((address_space(1))) void*)(W + b_base + 64 * INDIM + k0),
        (__attribute__((address_space(3))) void*)ldsB1, 16, 0, 0);
    __syncthreads();

    bf16x8 af[4], bfv[4];
#pragma unroll
    for (int m = 0; m < 4; ++m)
      af[m] = *(const bf16x8*)&As[(64 * wr + 16 * m + ln) * 32 + 8 * g];
#pragma unroll
    for (int n = 0; n < 4; ++n)
      bfv[n] = *(const bf16x8*)&Bs[(64 * wc + 16 * n + ln) * 32 + 8 * g];
#pragma unroll
    for (int m = 0; m < 4; ++m)
#pragma unroll
      for (int n = 0; n < 4; ++n)
        acc[m][n] = __builtin_amdgcn_mfma_f32_16x16x32_bf16(af[m], bfv[n], acc[m][n], 0, 0, 0);
  }

  // ---- epilogue ----  C: row = bm+64wr+16m+4g+r, col e = bn+64wc+16n+ln
  if (MODE == 1) {
#pragma unroll
    for (int n = 0; n < 4; ++n) {
      const int e = bn + 64 * wc + 16 * n + ln;
      const float bv = b0[e];
#pragma unroll
      for (int m = 0; m < 4; ++m)
#pragma unroll
        for (int r = 0; r < 4; ++r) {
          const int row = bm + 64 * wr + 16 * m + 4 * g + r;
          outF[(size_t)row * EMB + e] = acc[m][n][r] + bv;
        }
    }
    return;
  }

  const int which = bn >> 9;
  const float* bias = (which == 0) ? b0 : (which == 1) ? b1 : b2;

  if (which < 2) {
    // Q gets the softmax scale folded in (log2 domain): 0.125 * log2(e)
    const float scl = (which == 0) ? 0.18033688f : 1.0f;
    ushort* dst = (which == 0) ? outQ : outK;
#pragma unroll
    for (int n = 0; n < 4; ++n) {
      const int e = (bn & 511) + 64 * wc + 16 * n + ln;
      const float bv = bias[e];
      const int h = e >> 6, d = e & 63;
#pragma unroll
      for (int m = 0; m < 4; ++m)
#pragma unroll
        for (int r = 0; r < 4; ++r) {
          const int row = bm + 64 * wr + 16 * m + 4 * g + r;
          const int b = row >> 11, nn = row & (SEQ - 1);
          dst[(((size_t)(b * NHEADS + h) * SEQ) + nn) * DH + d] =
              f2bf((acc[m][n][r] + bv) * scl);
        }
    }
  } else {
    // V: transpose through LDS, write V^T [B,H,Dh,N]
    __syncthreads();
#pragma unroll
    for (int n = 0; n < 4; ++n) {
      const int cl = 64 * wc + 16 * n + ln;
      const float bv = bias[(bn & 511) + cl];
#pragma unroll
      for (int m = 0; m < 4; ++m)
#pragma unroll
        for (int r = 0; r < 4; ++r) {
          const int rl = 64 * wr + 16 * m + 4 * g + r;
          Tl[cl * 140 + rl] = f2bf(acc[m][n][r] + bv);
        }
    }
    __syncthreads();
    const int c = tid >> 1;
    const int rh = (tid & 1) * 64;
    const int e = (bn & 511) + c;
    const int h = e >> 6, d = e & 63;
    const int b = bm >> 11;
    const int nn0 = (bm & (SEQ - 1)) + rh;
    ushort* drow = outVT + (((size_t)(b * NHEADS + h) * DH) + d) * SEQ + nn0;
#pragma unroll
    for (int j = 0; j < 8; ++j)
      *(bf16x8*)&drow[j * 8] = *(const bf16x8*)&Tl[c * 140 + rh + j * 8];
  }
}

// ---------------------------------------------------------------------------
// MFMA flash attention, KV-SPLIT x2 (flash-decode). 4 waves x 32 q-rows;
// each block handles half the KV range (16 steps of 64). Static-max softmax
// (R4 bound argument) makes combining trivial: partial O and partial denom
// are summed via f32 atomicAdd into a zeroed buffer (exactly 2 contributions
// per element -> deterministic). Grid 1024 -> 4 blocks/CU (was 2).
// Ones-augmented PV computes the denominator in the accumulator.
// exp2 = raw v_exp_f32; prefetch via pointer increments (T14).
// T1 bijective XCD swizzle keeps 4 heads' K/V per XCD L2.
// ---------------------------------------------------------------------------
__global__ __launch_bounds__(256) void attn_mfma(const ushort* __restrict__ Q,
                                                 const ushort* __restrict__ K,
                                                 const ushort* __restrict__ VT,
                                                 float* __restrict__ P,
                                                 float* __restrict__ L) {
  __shared__ __align__(16) ushort Kl[64 * 72];     // [kv][d] padded
  __shared__ __align__(16) ushort Vl[80 * 72];     // [d][kv]; rows 64..79: ones-tile
  __shared__ __align__(16) ushort Pl[4][32 * 72];  // per-wave [q0..31][kv]

  const int tid = threadIdx.x;
  const int wave = tid >> 6, lane = tid & 63;
  const int g = lane >> 4, ln = lane & 15;

  // XCD swizzle over 1024 wgs: swz = (orig%8)*128 + orig/8 (bijective)
  const int orig = blockIdx.y * gridDim.x + blockIdx.x;
  const int swz = (orig & 7) * 128 + (orig >> 3);
  const int bh = swz >> 5;            // 0..31
  const int sub = swz & 31;
  const int qx = sub >> 1;            // 0..15
  const int half = sub & 1;           // kv half
  const int qbase = qx * 128 + wave * 32;
  const int kvbeg = half << 10;       // 0 or 1024

  // ones-tile init: d-local row 0 (LDS row 64) = 1.0, rows 65..79 = 0
  for (int i = tid; i < 16 * 72; i += 256)
    Vl[64 * 72 + i] = (i < 72) ? (ushort)0x3F80 : (ushort)0;

  const ushort* Qb = Q + ((size_t)bh * SEQ + qbase) * DH;
  const ushort* Kb = K + (size_t)bh * SEQ * DH;
  const ushort* Vb = VT + (size_t)bh * DH * SEQ;

  const bf16x8 qfA0 = *(const bf16x8*)&Qb[ln * DH + 8 * g];
  const bf16x8 qfA1 = *(const bf16x8*)&Qb[ln * DH + 32 + 8 * g];
  const bf16x8 qfB0 = *(const bf16x8*)&Qb[(16 + ln) * DH + 8 * g];
  const bf16x8 qfB1 = *(const bf16x8*)&Qb[(16 + ln) * DH + 32 + 8 * g];

  f32x4 oaccA[5], oaccB[5];
#pragma unroll
  for (int t = 0; t < 5; ++t) {
    oaccA[t] = (f32x4){0.f, 0.f, 0.f, 0.f};
    oaccB[t] = (f32x4){0.f, 0.f, 0.f, 0.f};
  }

  const int skv = tid >> 3, sd = (tid & 7) * 8;   // K staging
  const int dt = tid >> 2, kc = (tid & 3) * 8;    // V staging

  // prefetch pointers (incremented each iter; final prefetch is in-bounds junk)
  const ushort* kp0 = Kb + (size_t)(kvbeg + skv) * DH + sd;
  const ushort* kp1 = kp0 + 32 * DH;
  const ushort* vp0 = Vb + (size_t)dt * SEQ + kvbeg + kc;
  const ushort* vp1 = vp0 + 32;

  bf16x8 k0v = *(const bf16x8*)kp0;
  bf16x8 k1v = *(const bf16x8*)kp1;
  bf16x8 v0v = *(const bf16x8*)vp0;
  bf16x8 v1v = *(const bf16x8*)vp1;

  for (int it = 0; it < 16; ++it) {
    __syncthreads();   // prev tile consumed
    *(bf16x8*)&Kl[skv * 72 + sd] = k0v;
    *(bf16x8*)&Kl[(32 + skv) * 72 + sd] = k1v;
    *(bf16x8*)&Vl[dt * 72 + kc] = v0v;
    *(bf16x8*)&Vl[dt * 72 + 32 + kc] = v1v;

    // issue next tile's loads (fly during compute)
    kp0 += 64 * DH; kp1 += 64 * DH; vp0 += 64; vp1 += 64;
    k0v = *(const bf16x8*)kp0;
    k1v = *(const bf16x8*)kp1;
    v0v = *(const bf16x8*)vp0;
    v1v = *(const bf16x8*)vp1;

    asm volatile("s_waitcnt lgkmcnt(0)" ::: "memory");
    __builtin_amdgcn_s_barrier();

    // ---- QK^T: S^T[kv=16t+4g+r][q=ln (A) / 16+ln (B)] ----
    f32x4 saccA[4], saccB[4];
    __builtin_amdgcn_s_setprio(1);
#pragma unroll
    for (int t = 0; t < 4; ++t) {
      saccA[t] = (f32x4){0.f, 0.f, 0.f, 0.f};
      saccB[t] = (f32x4){0.f, 0.f, 0.f, 0.f};
      const bf16x8 ka0 = *(const bf16x8*)&Kl[(16 * t + ln) * 72 + 8 * g];
      const bf16x8 ka1 = *(const bf16x8*)&Kl[(16 * t + ln) * 72 + 32 + 8 * g];
      saccA[t] = __builtin_amdgcn_mfma_f32_16x16x32_bf16(ka0, qfA0, saccA[t], 0, 0, 0);
      saccA[t] = __builtin_amdgcn_mfma_f32_16x16x32_bf16(ka1, qfA1, saccA[t], 0, 0, 0);
      saccB[t] = __builtin_amdgcn_mfma_f32_16x16x32_bf16(ka0, qfB0, saccB[t], 0, 0, 0);
      saccB[t] = __builtin_amdgcn_mfma_f32_16x16x32_bf16(ka1, qfB1, saccB[t], 0, 0, 0);
    }
    __builtin_amdgcn_s_setprio(0);

    // ---- P = exp2(S), pack to LDS (same-wave; static max) ----
    ushort* Pw = Pl[wave];
#pragma unroll
    for (int t = 0; t < 4; ++t) {
      uint2 pkA, pkB;
      pkA.x = cvt_pk_bf16(fast_exp2(saccA[t][0]), fast_exp2(saccA[t][1]));
      pkA.y = cvt_pk_bf16(fast_exp2(saccA[t][2]), fast_exp2(saccA[t][3]));
      pkB.x = cvt_pk_bf16(fast_exp2(saccB[t][0]), fast_exp2(saccB[t][1]));
      pkB.y = cvt_pk_bf16(fast_exp2(saccB[t][2]), fast_exp2(saccB[t][3]));
      *(uint2*)&Pw[ln * 72 + 16 * t + 4 * g] = pkA;
      *(uint2*)&Pw[(16 + ln) * 72 + 16 * t + 4 * g] = pkB;
    }

    // ---- PV (+ ones-tile t=4 accumulates the denominator at col 0) ----
    __builtin_amdgcn_s_setprio(1);
#pragma unroll
    for (int c = 0; c < 2; ++c) {
      const bf16x8 paA = *(const bf16x8*)&Pw[ln * 72 + 32 * c + 8 * g];
      const bf16x8 paB = *(const bf16x8*)&Pw[(16 + ln) * 72 + 32 * c + 8 * g];
#pragma unroll
      for (int t = 0; t < 5; ++t) {
        const bf16x8 vb = *(const bf16x8*)&Vl[(16 * t + ln) * 72 + 32 * c + 8 * g];
        oaccA[t] = __builtin_amdgcn_mfma_f32_16x16x32_bf16(paA, vb, oaccA[t], 0, 0, 0);
        oaccB[t] = __builtin_amdgcn_mfma_f32_16x16x32_bf16(paB, vb, oaccB[t], 0, 0, 0);
      }
    }
    __builtin_amdgcn_s_setprio(0);
  }

  // ---- epilogue: accumulate partials (exactly 2 contributions/elem) ----
  const int b = bh >> 3, h = bh & 7;
#pragma unroll
  for (int r = 0; r < 4; ++r) {
    float* opA = P + (size_t)(b * SEQ + qbase + 4 * g + r) * EMB + h * 64;
    float* opB = opA + (size_t)16 * EMB;
#pragma unroll
    for (int t = 0; t < 4; ++t) {
      atomicAdd(&opA[16 * t + ln], oaccA[t][r]);
      atomicAdd(&opB[16 * t + ln], oaccB[t][r]);
    }
  }
  if (ln == 0) {   // denominator lives in col 0 of the ones-tile accumulator
#pragma unroll
    for (int r = 0; r < 4; ++r) {
      atomicAdd(&L[(size_t)(b * SEQ + qbase + 4 * g + r) * NHEADS + h], oaccA[4][r]);
      atomicAdd(&L[(size_t)(b * SEQ + qbase + 16 + 4 * g + r) * NHEADS + h], oaccB[4][r]);
    }
  }
}

// ---------------------------------------------------------------------------
// normalize: A_bf16[row][e] = P[row][e] / L[row][h],  8 elems/thread
// ---------------------------------------------------------------------------
__global__ __launch_bounds__(256) void normalize_o(const float* __restrict__ P,
                                                   const float* __restrict__ L,
                                                   ushort* __restrict__ A) {
  const int i = blockIdx.x * 256 + threadIdx.x;   // 524288 threads
  const int row = i >> 6;
  const int c = (i & 63) * 8;
  const int h = c >> 6;
  const float inv = 1.0f / L[(size_t)row * NHEADS + h];
  const float4 p0 = *(const float4*)&P[(size_t)row * EMB + c];
  const float4 p1 = *(const float4*)&P[(size_t)row * EMB + c + 4];
  uint4 o;
  o.x = cvt_pk_bf16(p0.x * inv, p0.y * inv);
  o.y = cvt_pk_bf16(p0.z * inv, p0.w * inv);
  o.z = cvt_pk_bf16(p1.x * inv, p1.y * inv);
  o.w = cvt_pk_bf16(p1.z * inv, p1.w * inv);
  ((uint4*)A)[i] = o;
}

// ---------------------------------------------------------------------------
extern "C" void kernel_launch(void* const* d_in, const int* in_sizes, int n_in,
                              void* d_out, int out_size, void* d_ws, size_t ws_size,
                              hipStream_t stream) {
  const float* q  = (const float*)d_in[0];
  const float* wq = (const float*)d_in[1];
  const float* bq = (const float*)d_in[2];
  const float* wk = (const float*)d_in[3];
  const float* bk = (const float*)d_in[4];
  const float* wv = (const float*)d_in[5];
  const float* bv = (const float*)d_in[6];
  const float* wo = (const float*)d_in[7];
  const float* bo = (const float*)d_in[8];
  float* out = (float*)d_out;

  // ws layout (ushort units):
  //   wsX  [0 .. 4M)      X bf16 (8 MB)
  //   wsW  [4M .. 5.25M)  weights bf16
  //   wsQ  [5.25M .. 9.4M)   Q bf16   (REUSED as wsA bf16 by normalize/gemm1)
  //   wsK  [9.4M .. 13.6M)   K bf16
  //   wsVT [13.6M .. 17.8M)  V^T bf16
  //   wsP  [17.8M .. 26.2M)  partial O f32 (16 MB, memset 0 each call)
  //   wsL  [26.2M .. +128K)  denom f32 (256 KB, memset 0 each call)
  const size_t XSZ = (size_t)MTOT * INDIM;            // 4,194,304
  const size_t WSZ = (size_t)EMB * INDIM;             // 262,144
  const size_t QSZ = (size_t)BATCH * NHEADS * SEQ * DH;
  ushort* wsX = (ushort*)d_ws;
  ushort* wsW = wsX + XSZ;
  ushort* wsQ = wsW + 4 * WSZ;
  ushort* wsK = wsQ + QSZ;
  ushort* wsVT = wsK + QSZ;
  float*  wsP = (float*)(wsVT + QSZ);
  float*  wsL = wsP + (size_t)MTOT * EMB;
  ushort* wsA = wsQ;   // overlay: Q dead after attn completes

  const dim3 blk(256);

  conv_bf16<<<dim3(XSZ / 8 / 256), blk, 0, stream>>>(q, wsX, XSZ / 8);
  conv_bf16_w4<<<dim3(WSZ / 8 / 256, 4), blk, 0, stream>>>(wq, wk, wv, wo, wsW, WSZ / 8);

  mfma_gemm<0><<<dim3(MTOT / 128, 1536 / 128), blk, 0, stream>>>(
      wsX, wsW, bq, bk, bv, wsQ, wsK, wsVT, nullptr);

  hipMemsetAsync(wsP, 0, (size_t)MTOT * EMB * sizeof(float) +
                          (size_t)MTOT * NHEADS * sizeof(float), stream);

  attn_mfma<<<dim3(32, 32), blk, 0, stream>>>(wsQ, wsK, wsVT, wsP, wsL);

  normalize_o<<<dim3(MTOT * EMB / 8 / 256), blk, 0, stream>>>(wsP, wsL, wsA);

  mfma_gemm<1><<<dim3(MTOT / 128, EMB / 128), blk, 0, stream>>>(
      wsA, wsW + 3 * WSZ, bo, nullptr, nullptr, nullptr, nullptr, nullptr, out);
}

// Round 8
// 123.871 us; speedup vs baseline: 1.0708x; 1.0708x over previous
//
#include <hip/hip_runtime.h>
#include <hip/hip_bf16.h>
#include <math.h>

#define SEQ    2048
#define DH     64
#define EMB    512
#define INDIM  512
#define NHEADS 8
#define BATCH  4
#define MTOT   (BATCH * SEQ)   // 8192

typedef __attribute__((ext_vector_type(8))) short bf16x8;   // 8 bf16 = 4 VGPR
typedef __attribute__((ext_vector_type(4))) float f32x4;

__device__ __forceinline__ ushort f2bf(float x) {
  union { float f; unsigned u; } v; v.f = x;
  unsigned r = v.u + 0x7FFFu + ((v.u >> 16) & 1u);   // RNE
  return (ushort)(r >> 16);
}

// packed f32x2 -> bf16x2 (single HW op)
__device__ __forceinline__ unsigned cvt_pk_bf16(float lo, float hi) {
  unsigned r;
  asm("v_cvt_pk_bf16_f32 %0, %1, %2" : "=v"(r) : "v"(lo), "v"(hi));
  return r;
}

// raw v_exp_f32 (exp2); args bounded (static-max softmax)
__device__ __forceinline__ float fast_exp2(float x) {
  float r;
  asm("v_exp_f32 %0, %1" : "=v"(r) : "v"(x));
  return r;
}

// v_permlane32_swap_b32: x.h1 <-> y.h0.  After: x = [x.h0, y.h0], y = [x.h1, y.h1]
__device__ __forceinline__ void permswap32(unsigned &x, unsigned &y) {
  asm("v_permlane32_swap_b32 %0, %1" : "+v"(x), "+v"(y));
}

// ---------------------------------------------------------------------------
// f32 -> bf16 conversion, 8 elems/thread
// ---------------------------------------------------------------------------
__global__ __launch_bounds__(256) void conv_bf16(const float* __restrict__ src,
                                                 ushort* __restrict__ dst, int n8) {
  const int i = blockIdx.x * 256 + threadIdx.x;
  if (i >= n8) return;
  const float4 a = ((const float4*)src)[i * 2];
  const float4 b = ((const float4*)src)[i * 2 + 1];
  uint4 o;
  o.x = cvt_pk_bf16(a.x, a.y);
  o.y = cvt_pk_bf16(a.z, a.w);
  o.z = cvt_pk_bf16(b.x, b.y);
  o.w = cvt_pk_bf16(b.z, b.w);
  ((uint4*)dst)[i] = o;
}

// 4 weight matrices in one launch (blockIdx.y selects)
__global__ __launch_bounds__(256) void conv_bf16_w4(
    const float* __restrict__ w0, const float* __restrict__ w1,
    const float* __restrict__ w2, const float* __restrict__ w3,
    ushort* __restrict__ dst, int n8per) {
  const int i = blockIdx.x * 256 + threadIdx.x;
  if (i >= n8per) return;
  const float* src = (blockIdx.y == 0) ? w0 : (blockIdx.y == 1) ? w1
                   : (blockIdx.y == 2) ? w2 : w3;
  ushort* d = dst + (size_t)blockIdx.y * n8per * 8;
  const float4 a = ((const float4*)src)[i * 2];
  const float4 b = ((const float4*)src)[i * 2 + 1];
  uint4 o;
  o.x = cvt_pk_bf16(a.x, a.y);
  o.y = cvt_pk_bf16(a.z, a.w);
  o.z = cvt_pk_bf16(b.x, b.y);
  o.w = cvt_pk_bf16(b.z, b.w);
  ((uint4*)d)[i] = o;
}

// ---------------------------------------------------------------------------
// MFMA GEMM, m97 structure: 128x128 tile, BK=32, 4 waves, 4x4 16x16 frags/wave,
// global_load_lds width 16.
// MODE 0: fused QKV (N=1536). which=bn>>9: 0->Q (pre-scaled by 0.125*log2e),
//         1->K bf16 [B,H,N,Dh]; 2->V^T bf16 [B,H,Dh,N] via LDS transpose.
// MODE 1: out-projection, f32 out [M][EMB] + bias.
// ---------------------------------------------------------------------------
template <int MODE>
__global__ __launch_bounds__(256) void mfma_gemm(
    const ushort* __restrict__ A, const ushort* __restrict__ W,
    const float* __restrict__ b0, const float* __restrict__ b1,
    const float* __restrict__ b2,
    ushort* __restrict__ outQ, ushort* __restrict__ outK,
    ushort* __restrict__ outVT, float* __restrict__ outF) {
  __shared__ __align__(16) char smem[MODE == 0 ? 35840 : 16384];
  ushort* As = (ushort*)smem;            // [128][32] bf16 = 8 KB
  ushort* Bs = (ushort*)(smem + 8192);   // [128][32] bf16 = 8 KB
  ushort* Tl = (ushort*)smem;            // epilogue transpose [128][140]

  const int bm = blockIdx.x * 128;
  const int bn = blockIdx.y * 128;
  const int tid = threadIdx.x;
  const int wave = tid >> 6, lane = tid & 63;
  const int g = lane >> 4, ln = lane & 15;
  const int wr = wave >> 1, wc = wave & 1;

  f32x4 acc[4][4];
#pragma unroll
  for (int m = 0; m < 4; ++m)
#pragma unroll
    for (int n = 0; n < 4; ++n) acc[m][n] = (f32x4){0.f, 0.f, 0.f, 0.f};

  const size_t a_base = (size_t)(bm + wave * 16 + (lane >> 2)) * INDIM + (lane & 3) * 8;
  const size_t b_base = (size_t)(bn + wave * 16 + (lane >> 2)) * INDIM + (lane & 3) * 8;
  ushort* ldsA0 = As + wave * 512;
  ushort* ldsA1 = As + 2048 + wave * 512;
  ushort* ldsB0 = Bs + wave * 512;
  ushort* ldsB1 = Bs + 2048 + wave * 512;

  for (int k0 = 0; k0 < INDIM; k0 += 32) {
    __syncthreads();
    __builtin_amdgcn_global_load_lds(
        (const __attribute__((address_space(1))) void*)(A + a_base + k0),
        (__attribute__((address_space(3))) void*)ldsA0, 16, 0, 0);
    __builtin_amdgcn_global_load_lds(
        (const __attribute__((address_space(1))) void*)(A + a_base + 64 * INDIM + k0),
        (__attribute__((address_space(3))) void*)ldsA1, 16, 0, 0);
    __builtin_amdgcn_global_load_lds(
        (const __attribute__((address_space(1))) void*)(W + b_base + k0),
        (__attribute__((address_space(3))) void*)ldsB0, 16, 0, 0);
    __builtin_amdgcn_global_load_lds(
        (const __attribute__((address_space(1))) void*)(W + b_base + 64 * INDIM + k0),
        (__attribute__((address_space(3))) void*)ldsB1, 16, 0, 0);
    __syncthreads();

    bf16x8 af[4], bfv[4];
#pragma unroll
    for (int m = 0; m < 4; ++m)
      af[m] = *(const bf16x8*)&As[(64 * wr + 16 * m + ln) * 32 + 8 * g];
#pragma unroll
    for (int n = 0; n < 4; ++n)
      bfv[n] = *(const bf16x8*)&Bs[(64 * wc + 16 * n + ln) * 32 + 8 * g];
#pragma unroll
    for (int m = 0; m < 4; ++m)
#pragma unroll
      for (int n = 0; n < 4; ++n)
        acc[m][n] = __builtin_amdgcn_mfma_f32_16x16x32_bf16(af[m], bfv[n], acc[m][n], 0, 0, 0);
  }

  // ---- epilogue ----  C: row = bm+64wr+16m+4g+r, col e = bn+64wc+16n+ln
  if (MODE == 1) {
#pragma unroll
    for (int n = 0; n < 4; ++n) {
      const int e = bn + 64 * wc + 16 * n + ln;
      const float bv = b0[e];
#pragma unroll
      for (int m = 0; m < 4; ++m)
#pragma unroll
        for (int r = 0; r < 4; ++r) {
          const int row = bm + 64 * wr + 16 * m + 4 * g + r;
          outF[(size_t)row * EMB + e] = acc[m][n][r] + bv;
        }
    }
    return;
  }

  const int which = bn >> 9;
  const float* bias = (which == 0) ? b0 : (which == 1) ? b1 : b2;

  if (which < 2) {
    // Q gets the softmax scale folded in (log2 domain): 0.125 * log2(e)
    const float scl = (which == 0) ? 0.18033688f : 1.0f;
    ushort* dst = (which == 0) ? outQ : outK;
#pragma unroll
    for (int n = 0; n < 4; ++n) {
      const int e = (bn & 511) + 64 * wc + 16 * n + ln;
      const float bv = bias[e];
      const int h = e >> 6, d = e & 63;
#pragma unroll
      for (int m = 0; m < 4; ++m)
#pragma unroll
        for (int r = 0; r < 4; ++r) {
          const int row = bm + 64 * wr + 16 * m + 4 * g + r;
          const int b = row >> 11, nn = row & (SEQ - 1);
          dst[(((size_t)(b * NHEADS + h) * SEQ) + nn) * DH + d] =
              f2bf((acc[m][n][r] + bv) * scl);
        }
    }
  } else {
    // V: transpose through LDS, write V^T [B,H,Dh,N]
    __syncthreads();
#pragma unroll
    for (int n = 0; n < 4; ++n) {
      const int cl = 64 * wc + 16 * n + ln;
      const float bv = bias[(bn & 511) + cl];
#pragma unroll
      for (int m = 0; m < 4; ++m)
#pragma unroll
        for (int r = 0; r < 4; ++r) {
          const int rl = 64 * wr + 16 * m + 4 * g + r;
          Tl[cl * 140 + rl] = f2bf(acc[m][n][r] + bv);
        }
    }
    __syncthreads();
    const int c = tid >> 1;
    const int rh = (tid & 1) * 64;
    const int e = (bn & 511) + c;
    const int h = e >> 6, d = e & 63;
    const int b = bm >> 11;
    const int nn0 = (bm & (SEQ - 1)) + rh;
    ushort* drow = outVT + (((size_t)(b * NHEADS + h) * DH) + d) * SEQ + nn0;
#pragma unroll
    for (int j = 0; j < 8; ++j)
      *(bf16x8*)&drow[j * 8] = *(const bf16x8*)&Tl[c * 140 + rh + j * 8];
  }
}

// ---------------------------------------------------------------------------
// MFMA flash attention, LDS-lean: 4 waves x 64 q-rows = 256 q/block; KV-step 64;
// kv-split x2 (grid 512 = 32bh x 8qx x 2half; XCD swizzle -> 4 bh per XCD).
// Key structure: P never touches LDS. K rows are staged permuted
// (pi: rows 4-7 <-> 8-11 per 16-tile, i.e. XOR 12 where bit2^bit3), so after
// swapped QK^T + cvt_pk packing, two v_permlane32_swap per c-half produce the
// PV A-fragment directly in registers:
//   A0,A2 = permswap(pk[2c][0], pk[2c+1][0]);  A1,A3 = permswap(pk[2c][1], pk[2c+1][1])
// K/V LDS fragments (ka[8], vb[8]) are read ONCE per iter and reused by all
// 4 q-groups -> LDS bytes/work drops ~2.7x vs R6 (was the measured roofline).
// Static-max softmax (R4 bound); denominator = in-lane f32 sum + 2 shfl_xor.
// Partials combined via f32 atomicAdd (exactly 2 contributions -> deterministic).
// ---------------------------------------------------------------------------
__global__ __launch_bounds__(256, 2) void attn_mfma(const ushort* __restrict__ Q,
                                                    const ushort* __restrict__ K,
                                                    const ushort* __restrict__ VT,
                                                    float* __restrict__ P,
                                                    float* __restrict__ L) {
  __shared__ __align__(16) ushort Kl[64 * 72];     // [kv(pi-permuted)][d] padded
  __shared__ __align__(16) ushort Vl[64 * 72];     // [d][kv] padded

  const int tid = threadIdx.x;
  const int wave = tid >> 6, lane = tid & 63;
  const int g = lane >> 4, ln = lane & 15;

  // XCD swizzle over 512 wgs: swz = (orig%8)*64 + orig/8 (bijective; 4 bh/XCD)
  const int orig = blockIdx.x;
  const int swz = (orig & 7) * 64 + (orig >> 3);
  const int bh = swz >> 4;            // 0..31
  const int sub = swz & 15;
  const int qx = sub >> 1;            // 0..7
  const int half = sub & 1;           // kv half
  const int qbase = qx * 256 + wave * 64;
  const int kvbeg = half << 10;       // 0 or 1024

  const ushort* Qb = Q + ((size_t)bh * SEQ + qbase) * DH;
  const ushort* Kb = K + (size_t)bh * SEQ * DH;
  const ushort* Vb = VT + (size_t)bh * DH * SEQ;

  // Q B-fragments for 4 q-groups (q = 16X + ln), two d-halves each
  bf16x8 qf[4][2];
#pragma unroll
  for (int X = 0; X < 4; ++X) {
    qf[X][0] = *(const bf16x8*)&Qb[(16 * X + ln) * DH + 8 * g];
    qf[X][1] = *(const bf16x8*)&Qb[(16 * X + ln) * DH + 32 + 8 * g];
  }

  f32x4 oacc[4][4];
#pragma unroll
  for (int X = 0; X < 4; ++X)
#pragma unroll
    for (int t = 0; t < 4; ++t) oacc[X][t] = (f32x4){0.f, 0.f, 0.f, 0.f};
  float denom[4] = {0.f, 0.f, 0.f, 0.f};

  const int skv = tid >> 3, sd = (tid & 7) * 8;   // K staging (rows skv, skv+32)
  const int dt = tid >> 2, kc = (tid & 3) * 8;    // V staging (d-row dt, cols kc, kc+32)
  // pi-permuted LDS rows for K: XOR 12 where bit2^bit3 (swaps rows 4-7 <-> 8-11)
  const int pr0 = skv ^ (((((skv >> 2) ^ (skv >> 3)) & 1)) * 12);
  const int s32 = skv + 32;
  const int pr1 = s32 ^ (((((s32 >> 2) ^ (s32 >> 3)) & 1)) * 12);

  const ushort* kp0 = Kb + (size_t)(kvbeg + skv) * DH + sd;
  const ushort* kp1 = kp0 + 32 * DH;
  const ushort* vp0 = Vb + (size_t)dt * SEQ + kvbeg + kc;
  const ushort* vp1 = vp0 + 32;

  bf16x8 k0v = *(const bf16x8*)kp0;
  bf16x8 k1v = *(const bf16x8*)kp1;
  bf16x8 v0v = *(const bf16x8*)vp0;
  bf16x8 v1v = *(const bf16x8*)vp1;

  for (int it = 0; it < 16; ++it) {
    __syncthreads();   // prev tile consumed
    *(bf16x8*)&Kl[pr0 * 72 + sd] = k0v;
    *(bf16x8*)&Kl[pr1 * 72 + sd] = k1v;
    *(bf16x8*)&Vl[dt * 72 + kc] = v0v;
    *(bf16x8*)&Vl[dt * 72 + 32 + kc] = v1v;

    // issue next tile's loads (fly during compute; raw barrier won't drain vmcnt)
    const size_t kadv = (it < 15) ? (size_t)(64 * DH) : 0;
    const int vadv = (it < 15) ? 64 : 0;
    kp0 += kadv; kp1 += kadv; vp0 += vadv; vp1 += vadv;
    k0v = *(const bf16x8*)kp0;
    k1v = *(const bf16x8*)kp1;
    v0v = *(const bf16x8*)vp0;
    v1v = *(const bf16x8*)vp1;

    asm volatile("s_waitcnt lgkmcnt(0)" ::: "memory");
    __builtin_amdgcn_s_barrier();

    // ---- shared fragments, read ONCE, reused by all 4 q-groups ----
    bf16x8 ka[4][2], vb[2][4];
#pragma unroll
    for (int t = 0; t < 4; ++t) {
      ka[t][0] = *(const bf16x8*)&Kl[(16 * t + ln) * 72 + 8 * g];
      ka[t][1] = *(const bf16x8*)&Kl[(16 * t + ln) * 72 + 32 + 8 * g];
    }
#pragma unroll
    for (int c = 0; c < 2; ++c)
#pragma unroll
      for (int t = 0; t < 4; ++t)
        vb[c][t] = *(const bf16x8*)&Vl[(16 * t + ln) * 72 + 32 * c + 8 * g];

#pragma unroll
    for (int X = 0; X < 4; ++X) {
      // ---- QK^T: sacc[t][r] = S(q=ln, kv = 16t + pi(4g+r)) ----
      f32x4 s0 = (f32x4){0.f, 0.f, 0.f, 0.f};
      f32x4 s1 = s0, s2 = s0, s3 = s0;
      __builtin_amdgcn_s_setprio(1);
      s0 = __builtin_amdgcn_mfma_f32_16x16x32_bf16(ka[0][0], qf[X][0], s0, 0, 0, 0);
      s1 = __builtin_amdgcn_mfma_f32_16x16x32_bf16(ka[1][0], qf[X][0], s1, 0, 0, 0);
      s2 = __builtin_amdgcn_mfma_f32_16x16x32_bf16(ka[2][0], qf[X][0], s2, 0, 0, 0);
      s3 = __builtin_amdgcn_mfma_f32_16x16x32_bf16(ka[3][0], qf[X][0], s3, 0, 0, 0);
      s0 = __builtin_amdgcn_mfma_f32_16x16x32_bf16(ka[0][1], qf[X][1], s0, 0, 0, 0);
      s1 = __builtin_amdgcn_mfma_f32_16x16x32_bf16(ka[1][1], qf[X][1], s1, 0, 0, 0);
      s2 = __builtin_amdgcn_mfma_f32_16x16x32_bf16(ka[2][1], qf[X][1], s2, 0, 0, 0);
      s3 = __builtin_amdgcn_mfma_f32_16x16x32_bf16(ka[3][1], qf[X][1], s3, 0, 0, 0);
      __builtin_amdgcn_s_setprio(0);

      // ---- P = exp2(S) (static max) ----
      float p0[4], p1[4], p2[4], p3[4];
#pragma unroll
      for (int r = 0; r < 4; ++r) {
        p0[r] = fast_exp2(s0[r]);
        p1[r] = fast_exp2(s1[r]);
        p2[r] = fast_exp2(s2[r]);
        p3[r] = fast_exp2(s3[r]);
      }

      // ---- denominator: in-lane 16-sum + cross-group reduce ----
      float ds = ((p0[0] + p0[1]) + (p0[2] + p0[3]))
               + ((p1[0] + p1[1]) + (p1[2] + p1[3]))
               + ((p2[0] + p2[1]) + (p2[2] + p2[3]))
               + ((p3[0] + p3[1]) + (p3[2] + p3[3]));
      ds += __shfl_xor(ds, 16);
      ds += __shfl_xor(ds, 32);
      denom[X] += ds;

      // ---- pack + permlane -> PV A-fragments (no LDS) ----
      unsigned a0 = cvt_pk_bf16(p0[0], p0[1]);
      unsigned a2 = cvt_pk_bf16(p1[0], p1[1]);
      unsigned a1 = cvt_pk_bf16(p0[2], p0[3]);
      unsigned a3 = cvt_pk_bf16(p1[2], p1[3]);
      permswap32(a0, a2);
      permswap32(a1, a3);
      unsigned b0 = cvt_pk_bf16(p2[0], p2[1]);
      unsigned b2 = cvt_pk_bf16(p3[0], p3[1]);
      unsigned b1 = cvt_pk_bf16(p2[2], p2[3]);
      unsigned b3 = cvt_pk_bf16(p3[2], p3[3]);
      permswap32(b0, b2);
      permswap32(b1, b3);
      union { unsigned u[4]; bf16x8 v; } pa0, pa1;
      pa0.u[0] = a0; pa0.u[1] = a1; pa0.u[2] = a2; pa0.u[3] = a3;
      pa1.u[0] = b0; pa1.u[1] = b1; pa1.u[2] = b2; pa1.u[3] = b3;

      // ---- PV ----
      __builtin_amdgcn_s_setprio(1);
#pragma unroll
      for (int t = 0; t < 4; ++t) {
        oacc[X][t] = __builtin_amdgcn_mfma_f32_16x16x32_bf16(pa0.v, vb[0][t], oacc[X][t], 0, 0, 0);
        oacc[X][t] = __builtin_amdgcn_mfma_f32_16x16x32_bf16(pa1.v, vb[1][t], oacc[X][t], 0, 0, 0);
      }
      __builtin_amdgcn_s_setprio(0);
    }
  }

  // ---- epilogue: accumulate partials (exactly 2 contributions/elem) ----
  const int b = bh >> 3, h = bh & 7;
#pragma unroll
  for (int X = 0; X < 4; ++X)
#pragma unroll
    for (int r = 0; r < 4; ++r) {
      float* op = P + (size_t)(b * SEQ + qbase + 16 * X + 4 * g + r) * EMB + h * 64;
#pragma unroll
      for (int t = 0; t < 4; ++t) atomicAdd(&op[16 * t + ln], oacc[X][t][r]);
    }
  if (g == 0) {
#pragma unroll
    for (int X = 0; X < 4; ++X)
      atomicAdd(&L[(size_t)(b * SEQ + qbase + 16 * X + ln) * NHEADS + h], denom[X]);
  }
}

// ---------------------------------------------------------------------------
// normalize: A_bf16[row][e] = P[row][e] / L[row][h],  8 elems/thread
// ---------------------------------------------------------------------------
__global__ __launch_bounds__(256) void normalize_o(const float* __restrict__ P,
                                                   const float* __restrict__ L,
                                                   ushort* __restrict__ A) {
  const int i = blockIdx.x * 256 + threadIdx.x;
  const int row = i >> 6;
  const int c = (i & 63) * 8;
  const int h = c >> 6;
  const float inv = 1.0f / L[(size_t)row * NHEADS + h];
  const float4 p0 = *(const float4*)&P[(size_t)row * EMB + c];
  const float4 p1 = *(const float4*)&P[(size_t)row * EMB + c + 4];
  uint4 o;
  o.x = cvt_pk_bf16(p0.x * inv, p0.y * inv);
  o.y = cvt_pk_bf16(p0.z * inv, p0.w * inv);
  o.z = cvt_pk_bf16(p1.x * inv, p1.y * inv);
  o.w = cvt_pk_bf16(p1.z * inv, p1.w * inv);
  ((uint4*)A)[i] = o;
}

// ---------------------------------------------------------------------------
extern "C" void kernel_launch(void* const* d_in, const int* in_sizes, int n_in,
                              void* d_out, int out_size, void* d_ws, size_t ws_size,
                              hipStream_t stream) {
  const float* q  = (const float*)d_in[0];
  const float* wq = (const float*)d_in[1];
  const float* bq = (const float*)d_in[2];
  const float* wk = (const float*)d_in[3];
  const float* bk = (const float*)d_in[4];
  const float* wv = (const float*)d_in[5];
  const float* bv = (const float*)d_in[6];
  const float* wo = (const float*)d_in[7];
  const float* bo = (const float*)d_in[8];
  float* out = (float*)d_out;

  const size_t XSZ = (size_t)MTOT * INDIM;
  const size_t WSZ = (size_t)EMB * INDIM;
  const size_t QSZ = (size_t)BATCH * NHEADS * SEQ * DH;
  ushort* wsX = (ushort*)d_ws;
  ushort* wsW = wsX + XSZ;
  ushort* wsQ = wsW + 4 * WSZ;
  ushort* wsK = wsQ + QSZ;
  ushort* wsVT = wsK + QSZ;
  float*  wsP = (float*)(wsVT + QSZ);
  float*  wsL = wsP + (size_t)MTOT * EMB;
  ushort* wsA = wsQ;   // overlay: Q dead after attn completes

  const dim3 blk(256);

  conv_bf16<<<dim3(XSZ / 8 / 256), blk, 0, stream>>>(q, wsX, XSZ / 8);
  conv_bf16_w4<<<dim3(WSZ / 8 / 256, 4), blk, 0, stream>>>(wq, wk, wv, wo, wsW, WSZ / 8);

  mfma_gemm<0><<<dim3(MTOT / 128, 1536 / 128), blk, 0, stream>>>(
      wsX, wsW, bq, bk, bv, wsQ, wsK, wsVT, nullptr);

  hipMemsetAsync(wsP, 0, (size_t)MTOT * EMB * sizeof(float) +
                          (size_t)MTOT * NHEADS * sizeof(float), stream);

  attn_mfma<<<dim3(512), blk, 0, stream>>>(wsQ, wsK, wsVT, wsP, wsL);

  normalize_o<<<dim3(MTOT * EMB / 8 / 256), blk, 0, stream>>>(wsP, wsL, wsA);

  mfma_gemm<1><<<dim3(MTOT / 128, EMB / 128), blk, 0, stream>>>(
      wsA, wsW + 3 * WSZ, bo, nullptr, nullptr, nullptr, nullptr, nullptr, out);
}